// Round 7
// baseline (41232.730 us; speedup 1.0000x reference)
//
#include <hip/hip_runtime.h>
#include <math.h>

#define L_   4
#define H_   8
#define D_   512
#define DH   64
#define DFF_ 2048
#define V_   8000
#define B_   16
#define SENC 128
#define T_   32
#define TP1  33
#define NEGV -1e9f
#define EPSV 1e-6f
#define SQRTD 22.627416997969522f
#define XSZ  ((size_t)TP1 * B_ * D_)     // 270336 floats
#define KVL  ((size_t)B_ * SENC * D_)    // per-layer cross K/V elems
#define G_   256                          // persistent grid: 1 block per CU

struct Prm {
    const float *enc, *pm, *embed, *wq, *wk, *wv, *wo, *cwq, *cwk, *cwv, *cwo,
                *w1, *b1, *w2, *b2, *ln_g, *ln_b, *fcw, *fcb;
    float *x, *xemb, *qkv, *parts, *ffnh, *cand_v, *KcT, *Vc, *cmask;
    int *cand_i, *tokens, *done, *bar, *outp;
};

union SMem {
    struct { float As[2][16][34]; float Bs[2][16][68]; } g;          // 13 KB
    struct { float qa[4][D_]; float xs[4][D_]; float scs[4][H_][SENC];
             float inv[4][H_]; } a;                                   // 32 KB
    struct { float xs[B_][D_]; float red[4][64][B_]; } lg;            // 48 KB
    struct { float sv[128]; int si[128]; } am;
};

// Software grid barrier (monotone epoch, no reset — max ~706*256 < 2^31).
// Requires all G_ blocks resident: enforced by 86KB LDS -> 1 block/CU.
__device__ __forceinline__ void gsync(int* cnt, int& epoch) {
    __syncthreads();
    if (threadIdx.x == 0) {
        __threadfence();                       // release prior writes
        epoch++;
        atomicAdd(cnt, 1);
        while (atomicAdd(cnt, 0) < epoch * G_)
            __builtin_amdgcn_s_sleep(8);
        __threadfence();                       // acquire others' writes
    }
    __syncthreads();
}

__device__ __forceinline__ float block_sum(float s, float* red) {
    #pragma unroll
    for (int off = 32; off; off >>= 1) s += __shfl_xor(s, off);
    if ((threadIdx.x & 63) == 0) red[threadIdx.x >> 6] = s;
    __syncthreads();
    float tot = red[0] + red[1] + red[2] + red[3];
    __syncthreads();
    return tot;
}

// 32x64 tile GEMM, double-buffered. tmode: 0 row-major, 1 KcT, 2 kT(TP1)
__device__ void gemm_tile(float As[2][16][34], float Bs[2][16][68],
    const float* __restrict__ A, const float* __restrict__ W,
    const float* __restrict__ bias, float* __restrict__ C,
    int M, int N, int K, int m0, int n0, int kbeg, int niter,
    int relu, int tmode)
{
    int tid = threadIdx.x;
    int tx = tid & 15, ty = tid >> 4;
    int am = tid >> 2, aseg = tid & 3;
    int bk = tid >> 4, bc4 = (tid & 15) * 4;
    float4 aReg = make_float4(0.f, 0.f, 0.f, 0.f), bReg;
    if (tid < 128) {
        int gm = m0 + am;
        if (gm < M) aReg = *(const float4*)&A[(size_t)gm * K + kbeg + aseg * 4];
    }
    bReg = *(const float4*)&W[(size_t)(kbeg + bk) * N + n0 + bc4];
    if (tid < 128) {
        As[0][aseg * 4 + 0][am] = aReg.x;
        As[0][aseg * 4 + 1][am] = aReg.y;
        As[0][aseg * 4 + 2][am] = aReg.z;
        As[0][aseg * 4 + 3][am] = aReg.w;
    }
    *(float4*)&Bs[0][bk][bc4] = bReg;
    __syncthreads();
    float acc[2][4] = {};
    for (int it = 0; it < niter; it++) {
        int cur = it & 1;
        if (it + 1 < niter) {
            int k0 = kbeg + (it + 1) * 16;
            if (tid < 128) {
                int gm = m0 + am;
                aReg = make_float4(0.f, 0.f, 0.f, 0.f);
                if (gm < M) aReg = *(const float4*)&A[(size_t)gm * K + k0 + aseg * 4];
            }
            bReg = *(const float4*)&W[(size_t)(k0 + bk) * N + n0 + bc4];
        }
        #pragma unroll
        for (int kk = 0; kk < 16; kk++) {
            float2 a2 = *(const float2*)&As[cur][kk][ty * 2];
            float4 b4 = *(const float4*)&Bs[cur][kk][tx * 4];
            acc[0][0] += a2.x * b4.x; acc[0][1] += a2.x * b4.y;
            acc[0][2] += a2.x * b4.z; acc[0][3] += a2.x * b4.w;
            acc[1][0] += a2.y * b4.x; acc[1][1] += a2.y * b4.y;
            acc[1][2] += a2.y * b4.z; acc[1][3] += a2.y * b4.w;
        }
        if (it + 1 < niter) {
            int nxt = 1 - cur;
            if (tid < 128) {
                As[nxt][aseg * 4 + 0][am] = aReg.x;
                As[nxt][aseg * 4 + 1][am] = aReg.y;
                As[nxt][aseg * 4 + 2][am] = aReg.z;
                As[nxt][aseg * 4 + 3][am] = aReg.w;
            }
            *(float4*)&Bs[nxt][bk][bc4] = bReg;
        }
        __syncthreads();
    }
    #pragma unroll
    for (int i = 0; i < 2; i++) {
        int gm = m0 + ty * 2 + i;
        if (gm >= M) continue;
        #pragma unroll
        for (int j = 0; j < 4; j++) {
            int gn = n0 + tx * 4 + j;
            float vv = acc[i][j];
            if (bias) vv += bias[gn];
            if (relu) vv = fmaxf(vv, 0.f);
            if (tmode == 0)
                C[(size_t)gm * N + gn] = vv;
            else if (tmode == 1)
                C[(size_t)(gm >> 7) * 65536 + (size_t)gn * SENC + (gm & 127)] = vv;
            else
                C[(size_t)(gm & 15) * 16896 + (size_t)gn * TP1 + (gm >> 4)] = vv;
        }
    }
}

__global__ __launch_bounds__(256) void decoder_k(Prm p)
{
    extern __shared__ char smem_raw[];
    SMem& sm = *(SMem*)smem_raw;
    __shared__ float bsred[4];
    int bid = blockIdx.x, tid = threadIdx.x;
    int c0 = tid * 2;
    int epoch = 0;

    // ---- init ----
    if (bid == 0) {
        for (int i = tid; i < B_ * TP1; i += 256)
            p.tokens[i] = ((i % TP1) == 0) ? 1 : 0;
        if (tid < B_) p.done[tid] = 0;
    }
    if (bid == 1) {
        for (int i = tid; i < B_ * SENC; i += 256)
            p.cmask[i] = p.pm[i] * NEGV;
    }
    gsync(p.bar, epoch);

    // ---- cross K/V precompute: 4 layers x {K,V} x 8 n-tiles x 64 row-tiles
    for (int job = bid; job < L_ * 1024; job += G_) {
        int l = job >> 10;
        int w = job & 1;
        int jn = (job >> 1) & 7;
        int mr = (job >> 4) & 63;
        gemm_tile(sm.g.As, sm.g.Bs, p.enc,
                  (w ? p.cwv : p.cwk) + (size_t)l * D_ * D_, nullptr,
                  (w ? p.Vc : p.KcT) + (size_t)l * KVL,
                  B_ * SENC, D_, D_, mr * 32, jn * 64, 0, 32, 0, w ? 0 : 1);
    }
    gsync(p.bar, epoch);

    for (int t = 0; t < T_; t++) {
        int P = t + 1;
        int M = P * B_;
        int mt = (M + 31) / 32;

        // ---- phase: argmax(prev step) + embed row t ----
        for (int job = bid; job < B_; job += G_) {
            int b = job;
            if (t > 0) {
                if (tid < 128) {
                    sm.am.sv[tid] = (tid < 125) ? p.cand_v[(size_t)b * 125 + tid] : -1e30f;
                    sm.am.si[tid] = (tid < 125) ? p.cand_i[(size_t)b * 125 + tid] : 0x7fffffff;
                }
                __syncthreads();
                for (int s = 64; s; s >>= 1) {
                    if (tid < s) {
                        float ov = sm.am.sv[tid + s]; int oi = sm.am.si[tid + s];
                        if (ov > sm.am.sv[tid] ||
                            (ov == sm.am.sv[tid] && oi < sm.am.si[tid])) {
                            sm.am.sv[tid] = ov; sm.am.si[tid] = oi;
                        }
                    }
                    __syncthreads();
                }
                if (tid == 0) {
                    int idx = sm.am.si[0];
                    int dn = p.done[b] | (idx == 2 ? 1 : 0);
                    p.done[b] = dn;
                    int tok = dn ? 0 : idx;
                    p.tokens[b * TP1 + t] = tok;
                    sm.am.si[0] = tok;
                }
                __syncthreads();
            } else {
                if (tid == 0) sm.am.si[0] = 1;   // START
                __syncthreads();
            }
            int tok = sm.am.si[0];
            const float* e = p.embed + (size_t)tok * D_;
            float* xr = p.xemb + ((size_t)t * B_ + b) * D_;
            #pragma unroll
            for (int u = 0; u < 2; u++) {
                int c = c0 + u;
                float fd = (float)(2 * (c / 2)) / (float)D_;
                float ang = (float)t / powf(10000.f, fd);
                float pe = (c & 1) ? cosf(ang) : sinf(ang);
                xr[c] = e[c] * SQRTD + pe;
            }
            __syncthreads();
        }
        gsync(p.bar, epoch);

        for (int l = 0; l < L_; l++) {
            const size_t lw = (size_t)l * D_ * D_;
            const float* lgam = p.ln_g + (size_t)l * 3 * D_;
            const float* lbet = p.ln_b + (size_t)l * 3 * D_;

            // ---- phase: QKV projection (+ xemb->x copy on l==0) ----
            const float* Aq = (l == 0) ? p.xemb : p.x;
            int jmod = (l == 0) ? 25 : 24;
            int nq = jmod * mt;
            for (int job = bid; job < nq; job += G_) {
                int jn = job % jmod;
                int mr = job / jmod;
                if (jn < 24) {
                    int sel = jn >> 3;
                    const float* W = (sel == 0) ? p.wq + lw
                                   : (sel == 1) ? p.wk + lw : p.wv + lw;
                    gemm_tile(sm.g.As, sm.g.Bs, Aq, W, nullptr,
                              p.qkv + (size_t)sel * XSZ, M, D_, D_,
                              mr * 32, (jn & 7) * 64, 0, 32, 0,
                              sel == 1 ? 2 : 0);
                } else {
                    for (int i = tid; i < 32 * 128; i += 256) {
                        int rr = mr * 32 + (i >> 7);
                        if (rr < M)
                            *(float4*)&p.x[(size_t)rr * D_ + (i & 127) * 4] =
                                *(const float4*)&p.xemb[(size_t)rr * D_ + (i & 127) * 4];
                    }
                }
            }
            gsync(p.bar, epoch);

            // ---- phase: mega attention (4 rows sharing batch b per block) ----
            int ng = ((P + 3) >> 2) * B_;
            for (int job = bid; job < ng; job += G_) {
                int b = job & 15;
                int g4 = job >> 4;
                int prow[4];
                #pragma unroll
                for (int rr = 0; rr < 4; rr++) {
                    int pp = 4 * g4 + rr;
                    prow[rr] = (pp < P ? pp : P - 1) * B_ + b;   // clamped
                }
                int nr = P - 4 * g4; if (nr > 4) nr = 4;
                for (int i = tid; i < 4 * 256; i += 256) {
                    int rr = i >> 8, cc = (i & 255) * 2;
                    *(float2*)&sm.a.qa[rr][cc] =
                        *(const float2*)&p.qkv[(size_t)prow[rr] * D_ + cc];
                }
                __syncthreads();
                // self scores
                {
                    int kp = tid & 31, h = tid >> 5;
                    float acc[4] = {};
                    if (kp < P) {
                        const float* kb = p.qkv + XSZ +
                            ((size_t)(b * 8 + h) * 64) * TP1 + kp;
                        for (int d = 0; d < 64; d++) {
                            float kv = kb[(size_t)d * TP1];
                            #pragma unroll
                            for (int rr = 0; rr < 4; rr++)
                                acc[rr] += sm.a.qa[rr][h * 64 + d] * kv;
                        }
                    }
                    #pragma unroll
                    for (int rr = 0; rr < 4; rr++)
                        sm.a.scs[rr][h][kp] = acc[rr] * 0.125f;
                }
                __syncthreads();
                if (tid < 32) {
                    int rr = tid >> 3, h = tid & 7;
                    float mx = -1e30f;
                    for (int j = 0; j < P; j++) mx = fmaxf(mx, sm.a.scs[rr][h][j]);
                    float sum = 0.f;
                    for (int j = 0; j < P; j++) {
                        float e = expf(sm.a.scs[rr][h][j] - mx);
                        sm.a.scs[rr][h][j] = e;
                        sum += e;
                    }
                    sm.a.inv[rr][h] = 1.f / sum;
                }
                __syncthreads();
                // weighted V
                {
                    int h = c0 >> 6;
                    float o0[4] = {}, o1[4] = {};
                    for (int j = 0; j < P; j++) {
                        float2 vv = *(const float2*)&p.qkv[2 * XSZ +
                            ((size_t)j * B_ + b) * D_ + c0];
                        #pragma unroll
                        for (int rr = 0; rr < 4; rr++) {
                            float w = sm.a.scs[rr][h][j];
                            o0[rr] += w * vv.x; o1[rr] += w * vv.y;
                        }
                    }
                    __syncthreads();
                    #pragma unroll
                    for (int rr = 0; rr < 4; rr++) {
                        float iv = sm.a.inv[rr][h];
                        sm.a.qa[rr][c0] = o0[rr] * iv;
                        sm.a.qa[rr][c0 + 1] = o1[rr] * iv;
                    }
                }
                __syncthreads();
                // wo out-proj + residual + LN -> xs
                {
                    float v0[4], v1[4];
                    #pragma unroll
                    for (int rr = 0; rr < 4; rr++) {
                        float2 xv = *(const float2*)&p.x[(size_t)prow[rr] * D_ + c0];
                        v0[rr] = xv.x; v1[rr] = xv.y;
                    }
                    for (int k = 0; k < D_; k++) {
                        float2 wv = *(const float2*)&p.wo[lw + (size_t)k * D_ + c0];
                        #pragma unroll
                        for (int rr = 0; rr < 4; rr++) {
                            float a = sm.a.qa[rr][k];
                            v0[rr] += a * wv.x; v1[rr] += a * wv.y;
                        }
                    }
                    for (int rr = 0; rr < 4; rr++) {
                        float mean = block_sum(v0[rr] + v1[rr], bsred) * (1.f / 512.f);
                        float d0 = v0[rr] - mean, d1 = v1[rr] - mean;
                        float var = block_sum(d0 * d0 + d1 * d1, bsred) * (1.f / 512.f);
                        float rs = rsqrtf(var + EPSV);
                        sm.a.xs[rr][c0]     = d0 * rs * lgam[c0]     + lbet[c0];
                        sm.a.xs[rr][c0 + 1] = d1 * rs * lgam[c0 + 1] + lbet[c0 + 1];
                    }
                }
                __syncthreads();
                // cross q-proj -> qa
                {
                    float q0[4] = {}, q1[4] = {};
                    for (int k = 0; k < D_; k++) {
                        float2 wv = *(const float2*)&p.cwq[lw + (size_t)k * D_ + c0];
                        #pragma unroll
                        for (int rr = 0; rr < 4; rr++) {
                            float a = sm.a.xs[rr][k];
                            q0[rr] += a * wv.x; q1[rr] += a * wv.y;
                        }
                    }
                    __syncthreads();
                    #pragma unroll
                    for (int rr = 0; rr < 4; rr++) {
                        sm.a.qa[rr][c0] = q0[rr];
                        sm.a.qa[rr][c0 + 1] = q1[rr];
                    }
                }
                __syncthreads();
                // cross scores
                #pragma unroll
                for (int jj = 0; jj < 4; jj++) {
                    int idx = tid + jj * 256;
                    int h = idx >> 7, s = idx & 127;
                    const float* kb = p.KcT + (size_t)l * KVL +
                        ((size_t)(b * 8 + h) * 64) * SENC + s;
                    float acc[4] = {};
                    for (int d = 0; d < 64; d++) {
                        float kv = kb[(size_t)d * SENC];
                        #pragma unroll
                        for (int rr = 0; rr < 4; rr++)
                            acc[rr] += sm.a.qa[rr][h * 64 + d] * kv;
                    }
                    float cm = p.cmask[b * SENC + s];
                    #pragma unroll
                    for (int rr = 0; rr < 4; rr++)
                        sm.a.scs[rr][h][s] = acc[rr] * 0.125f + cm;
                }
                __syncthreads();
                if (tid < 32) {
                    int rr = tid >> 3, h = tid & 7;
                    float mx = -1e30f;
                    for (int s = 0; s < SENC; s++) mx = fmaxf(mx, sm.a.scs[rr][h][s]);
                    float sum = 0.f;
                    for (int s = 0; s < SENC; s++) {
                        float e = expf(sm.a.scs[rr][h][s] - mx);
                        sm.a.scs[rr][h][s] = e;
                        sum += e;
                    }
                    sm.a.inv[rr][h] = 1.f / sum;
                }
                __syncthreads();
                // cross weighted V
                {
                    int h = c0 >> 6;
                    float o0[4] = {}, o1[4] = {};
                    for (int s = 0; s < SENC; s++) {
                        float2 vv = *(const float2*)&p.Vc[(size_t)l * KVL +
                            ((size_t)b * SENC + s) * D_ + c0];
                        #pragma unroll
                        for (int rr = 0; rr < 4; rr++) {
                            float w = sm.a.scs[rr][h][s];
                            o0[rr] += w * vv.x; o1[rr] += w * vv.y;
                        }
                    }
                    __syncthreads();
                    #pragma unroll
                    for (int rr = 0; rr < 4; rr++) {
                        float iv = sm.a.inv[rr][h];
                        sm.a.qa[rr][c0] = o0[rr] * iv;
                        sm.a.qa[rr][c0 + 1] = o1[rr] * iv;
                    }
                }
                __syncthreads();
                // cwo out-proj + residual(xs) + LN -> x
                {
                    float v0[4], v1[4];
                    #pragma unroll
                    for (int rr = 0; rr < 4; rr++) {
                        v0[rr] = sm.a.xs[rr][c0]; v1[rr] = sm.a.xs[rr][c0 + 1];
                    }
                    for (int k = 0; k < D_; k++) {
                        float2 wv = *(const float2*)&p.cwo[lw + (size_t)k * D_ + c0];
                        #pragma unroll
                        for (int rr = 0; rr < 4; rr++) {
                            float a = sm.a.qa[rr][k];
                            v0[rr] += a * wv.x; v1[rr] += a * wv.y;
                        }
                    }
                    for (int rr = 0; rr < 4; rr++) {
                        float mean = block_sum(v0[rr] + v1[rr], bsred) * (1.f / 512.f);
                        float d0 = v0[rr] - mean, d1 = v1[rr] - mean;
                        float var = block_sum(d0 * d0 + d1 * d1, bsred) * (1.f / 512.f);
                        float rs = rsqrtf(var + EPSV);
                        if (rr < nr) {
                            p.x[(size_t)prow[rr] * D_ + c0] =
                                d0 * rs * lgam[D_ + c0] + lbet[D_ + c0];
                            p.x[(size_t)prow[rr] * D_ + c0 + 1] =
                                d1 * rs * lgam[D_ + c0 + 1] + lbet[D_ + c0 + 1];
                        }
                    }
                }
                __syncthreads();
            }
            gsync(p.bar, epoch);

            // ---- phase: FFN1 (relu(x@w1+b1)) ----
            for (int job = bid; job < 32 * mt; job += G_) {
                int jn = job & 31, mr = job >> 5;
                gemm_tile(sm.g.As, sm.g.Bs, p.x,
                          p.w1 + (size_t)l * D_ * DFF_, p.b1 + (size_t)l * DFF_,
                          p.ffnh, M, DFF_, D_, mr * 32, jn * 64, 0, 32, 1, 0);
            }
            gsync(p.bar, epoch);

            // ---- phase: FFN2 split-K 4 ----
            for (int job = bid; job < 32 * mt; job += G_) {
                int kz = job & 3, jn = (job >> 2) & 7, mr = job >> 5;
                gemm_tile(sm.g.As, sm.g.Bs, p.ffnh,
                          p.w2 + (size_t)l * DFF_ * D_, nullptr,
                          p.parts + (size_t)kz * XSZ, M, D_, DFF_,
                          mr * 32, jn * 64, kz * 512, 32, 0, 0);
            }
            gsync(p.bar, epoch);

            // ---- phase: LN reduce ----
            for (int job = bid; job < M; job += G_) {
                float* xr = p.x + (size_t)job * D_;
                float v0 = xr[tid], v1 = xr[tid + 256];
                for (int s = 0; s < 4; s++) {
                    const float* pr = p.parts + (size_t)s * XSZ + (size_t)job * D_;
                    v0 += pr[tid]; v1 += pr[tid + 256];
                }
                v0 += p.b2[(size_t)l * D_ + tid];
                v1 += p.b2[(size_t)l * D_ + tid + 256];
                float mean = block_sum(v0 + v1, bsred) * (1.f / 512.f);
                float d0 = v0 - mean, d1 = v1 - mean;
                float var = block_sum(d0 * d0 + d1 * d1, bsred) * (1.f / 512.f);
                float rs = rsqrtf(var + EPSV);
                xr[tid]       = d0 * rs * lgam[2 * D_ + tid]       + lbet[2 * D_ + tid];
                xr[tid + 256] = d1 * rs * lgam[2 * D_ + tid + 256] + lbet[2 * D_ + tid + 256];
                __syncthreads();
            }
            gsync(p.bar, epoch);
        }

        // ---- phase: logits -> per-tile argmax candidates ----
        for (int job = bid; job < 125; job += G_) {
            for (int i = tid; i < B_ * D_; i += 256) {
                int b = i >> 9, d = i & 511;
                sm.lg.xs[b][d] = p.x[((size_t)t * B_ + b) * D_ + d];
            }
            __syncthreads();
            int lane = tid & 63, ks = tid >> 6;
            int col = job * 64 + lane;
            float acc[B_] = {};
            int kb = ks * 128;
            for (int k = kb; k < kb + 128; k++) {
                float w = p.fcw[(size_t)k * V_ + col];
                #pragma unroll
                for (int b = 0; b < B_; b++) acc[b] += sm.lg.xs[b][k] * w;
            }
            #pragma unroll
            for (int b = 0; b < B_; b++) sm.lg.red[ks][lane][b] = acc[b];
            __syncthreads();
            if (ks == 0) {
                float bias = p.fcb[col];
                #pragma unroll
                for (int b = 0; b < B_; b++) {
                    float val = sm.lg.red[0][lane][b] + sm.lg.red[1][lane][b]
                              + sm.lg.red[2][lane][b] + sm.lg.red[3][lane][b] + bias;
                    int idx = col;
                    #pragma unroll
                    for (int off = 32; off; off >>= 1) {
                        float ov = __shfl_down(val, off);
                        int oi = __shfl_down(idx, off);
                        if (ov > val || (ov == val && oi < idx)) { val = ov; idx = oi; }
                    }
                    if (lane == 0) {
                        p.cand_v[(size_t)b * 125 + job] = val;
                        p.cand_i[(size_t)b * 125 + job] = idx;
                    }
                }
            }
            __syncthreads();
        }
        gsync(p.bar, epoch);
    }

    // ---- final: argmax for position T_, write output ----
    for (int job = bid; job < B_; job += G_) {
        int b = job;
        if (tid < 128) {
            sm.am.sv[tid] = (tid < 125) ? p.cand_v[(size_t)b * 125 + tid] : -1e30f;
            sm.am.si[tid] = (tid < 125) ? p.cand_i[(size_t)b * 125 + tid] : 0x7fffffff;
        }
        __syncthreads();
        for (int s = 64; s; s >>= 1) {
            if (tid < s) {
                float ov = sm.am.sv[tid + s]; int oi = sm.am.si[tid + s];
                if (ov > sm.am.sv[tid] ||
                    (ov == sm.am.sv[tid] && oi < sm.am.si[tid])) {
                    sm.am.sv[tid] = ov; sm.am.si[tid] = oi;
                }
            }
            __syncthreads();
        }
        if (tid == 0) {
            int idx = sm.am.si[0];
            int dn = p.done[b] | (idx == 2 ? 1 : 0);
            sm.am.si[0] = dn ? 0 : idx;
        }
        __syncthreads();
        if (tid < T_) {
            int v = (tid == T_ - 1) ? sm.am.si[0] : p.tokens[b * TP1 + tid + 1];
            p.outp[b * T_ + tid] = v;
        }
        __syncthreads();
    }
}

// ---------------------------------------------------------------------------
extern "C" void kernel_launch(void* const* d_in, const int* in_sizes, int n_in,
                              void* d_out, int out_size, void* d_ws, size_t ws_size,
                              hipStream_t stream)
{
    Prm p;
    p.enc   = (const float*)d_in[1];
    p.pm    = (const float*)d_in[2];
    p.embed = (const float*)d_in[3];
    p.wq    = (const float*)d_in[4];
    p.wk    = (const float*)d_in[5];
    p.wv    = (const float*)d_in[6];
    p.wo    = (const float*)d_in[7];
    p.cwq   = (const float*)d_in[8];
    p.cwk   = (const float*)d_in[9];
    p.cwv   = (const float*)d_in[10];
    p.cwo   = (const float*)d_in[11];
    p.w1    = (const float*)d_in[12];
    p.b1    = (const float*)d_in[13];
    p.w2    = (const float*)d_in[14];
    p.b2    = (const float*)d_in[15];
    p.ln_g  = (const float*)d_in[16];
    p.ln_b  = (const float*)d_in[17];
    p.fcw   = (const float*)d_in[18];
    p.fcb   = (const float*)d_in[19];

    float* ws = (float*)d_ws;
    size_t off = 0;
    p.x      = ws + off; off += XSZ;
    p.xemb   = ws + off; off += XSZ;
    p.qkv    = ws + off; off += 3 * XSZ;
    p.parts  = ws + off; off += 4 * XSZ;
    p.ffnh   = ws + off; off += (size_t)TP1 * B_ * DFF_;
    p.cand_v = ws + off; off += (size_t)B_ * 125;
    p.KcT    = ws + off; off += (size_t)L_ * KVL;
    p.Vc     = ws + off; off += (size_t)L_ * KVL;
    p.cmask  = ws + off; off += (size_t)B_ * SENC;
    p.cand_i = (int*)(ws + off); off += (size_t)B_ * 125;
    p.tokens = (int*)(ws + off); off += (B_ * TP1 + 63) & ~63;
    p.done   = (int*)(ws + off); off += 64;
    p.bar    = (int*)(ws + off); off += 64;
    p.outp   = (int*)d_out;

    // Zero the barrier counter (d_ws is re-poisoned before every call).
    hipMemsetAsync(p.bar, 0, 256, stream);

    // 86KB dynamic LDS -> exactly 1 block/CU -> all 256 blocks co-resident.
    const int smem_bytes = 86016;
    hipFuncSetAttribute((const void*)decoder_k,
                        hipFuncAttributeMaxDynamicSharedMemorySize, smem_bytes);
    decoder_k<<<dim3(G_), dim3(256), smem_bytes, stream>>>(p);
}